// Round 1
// baseline (210.323 us; speedup 1.0000x reference)
//
#include <hip/hip_runtime.h>
#include <stdint.h>

// VectorQuantizer — bit-exact replication of the fp32 numpy reference.
//   d = sum(z*z,1)[:,None] + sum(c*c,1)[None,:] - 2.0*einsum('nc,kc->nk',z,c)
// sums: numpy pairwise_sum n=64 (8 accumulators + fixed tree). einsum: AVX512
// order — 16 chained-FMA lanes over 4 blocks of 16, then reduce_add tree.
//
// Round 1 changes vs. 196µs/154µs baseline:
//  (a) cnorm precomputed ONCE in a 2-block pre-kernel into d_ws (the in-block
//      preamble was TA-bound: each load touched 64 distinct cache lines, and
//      all 2048 blocks redid it). Main kernel loads 2KB coalesced into LDS.
//  (b) amdgpu_waves_per_eu(4,4): VGPR_Count=48 was impossible for zz2[32]
//      (64 VGPRs live across the whole k-loop) — the allocator had parked
//      zz2 in AGPRs with v_accvgpr_read copies in the hot loop (~64 junk
//      VALU/iter, matching the 2.6x VALU inflation). Pinning exactly 4
//      waves/EU gives a 128-arch-VGPR budget, removing the incentive.
//  (c) #pragma unroll 2 on the k-loop: overlap next iteration's s_loads
//      with current FMA chains.
//
// Channel-pair packing proven bit-exact (round 6 of prior session): VOP3P via
// inline asm, codebook row through SGPR pairs (wave-uniform s_load path),
// per-scalar ops and order identical to the scalar ref.
// Structure: 1 point/lane, 4-wave k-split, block = 64 points, 2048 blocks.
// Argmin over ascending disjoint k-ranges combined with strict <.

#pragma clang fp contract(off)

#define KCODES 512
#define CDIM 64
#define HW 4096              // 64*64
#define ZQ_ELEMS 8388608     // 32*64*64*64

typedef float f2 __attribute__((ext_vector_type(2)));

// d = {fma(a.x, b.lo, c.x), fma(a.y, b.hi, c.y)} — b is an SGPR pair
static __device__ __forceinline__ f2 pk_fma_s(f2 a, uint64_t b, f2 c) {
    f2 d;
    asm("v_pk_fma_f32 %0, %1, %2, %3" : "=v"(d) : "v"(a), "s"(b), "v"(c));
    return d;
}
static __device__ __forceinline__ f2 pk_add(f2 a, f2 b) {
    f2 d;
    asm("v_pk_add_f32 %0, %1, %2" : "=v"(d) : "v"(a), "v"(b));
    return d;
}

// np.sum(row*row): pairwise_sum n=64 replica (products pre-rounded), one row
static __device__ __forceinline__ float cnorm_row(const float* __restrict__ row) {
    float r[8];
    #pragma unroll
    for (int j = 0; j < 8; ++j) r[j] = row[j] * row[j];
    #pragma unroll
    for (int i = 8; i < 64; i += 8) {
        #pragma unroll
        for (int j = 0; j < 8; ++j) r[j] = r[j] + row[i + j] * row[i + j];
    }
    return ((r[0] + r[1]) + (r[2] + r[3])) + ((r[4] + r[5]) + (r[6] + r[7]));
}

// One-shot: cnorm[512] into workspace. 2 blocks x 256 threads.
__global__ void cnorm_kernel(const float* __restrict__ cb,
                             float* __restrict__ cnorm_out) {
    int k = (int)blockIdx.x * 256 + (int)threadIdx.x;
    if (k < KCODES) cnorm_out[k] = cnorm_row(cb + (size_t)k * CDIM);
}

__global__ __launch_bounds__(256)
__attribute__((amdgpu_waves_per_eu(4, 4)))
void vq_kernel(
    const float* __restrict__ z_e,
    const float* __restrict__ cb,
    const float* __restrict__ cnorm_g,   // precomputed (d_ws) or nullptr
    float* __restrict__ out)
{
    __shared__ float cnorm[KCODES];
    __shared__ float dcand[4 * 64];
    __shared__ int   kcand[4 * 64];

    if (cnorm_g) {
        // coalesced 2KB load: 2 x 4B/lane, stride-1
        #pragma unroll
        for (int k = (int)threadIdx.x; k < KCODES; k += 256)
            cnorm[k] = cnorm_g[k];
    } else {
        // fallback (ws too small): original in-block compute, bit-identical
        for (int k = (int)threadIdx.x; k < KCODES; k += 256)
            cnorm[k] = cnorm_row(cb + (size_t)k * CDIM);
    }

    // block = 64 consecutive points; wave g covers k in [128g, 128g+128)
    const int lane = (int)threadIdx.x & 63;
    const int g = __builtin_amdgcn_readfirstlane((int)threadIdx.x >> 6);
    const int n0 = (int)blockIdx.x * 64;
    const int b = n0 / HW;
    const int hw0 = n0 % HW;
    const float* zp = z_e + (size_t)b * CDIM * HW + hw0 + lane;

    // one point per lane; channel pairs packed: zz2[m] = {z[2m], z[2m+1]}
    f2 zz2[CDIM / 2];
    #pragma unroll
    for (int m = 0; m < CDIM / 2; ++m) {
        f2 t;
        t.x = zp[(size_t)(2 * m) * HW];
        t.y = zp[(size_t)(2 * m + 1) * HW];
        zz2[m] = t;
    }

    // np.sum(z*z, axis=1): pairwise replica, packed by channel pairs
    float sz;
    {
        f2 pr[4];
        #pragma unroll
        for (int t = 0; t < 4; ++t) pr[t] = zz2[t] * zz2[t];
        #pragma unroll
        for (int i = 8; i < 64; i += 8) {
            #pragma unroll
            for (int t = 0; t < 4; ++t) {
                f2 zt = zz2[(i + 2 * t) / 2];
                pr[t] = pr[t] + zt * zt;
            }
        }
        float s01 = pr[0].x + pr[0].y;
        float s23 = pr[1].x + pr[1].y;
        float s45 = pr[2].x + pr[2].y;
        float s67 = pr[3].x + pr[3].y;
        sz = (s01 + s23) + (s45 + s67);
    }

    __syncthreads();

    f2 zero; zero.x = 0.f; zero.y = 0.f;   // hoisted VGPR pair for chain tails

    float best = 3.4e38f;
    int bk = 0;
    const int k0 = g * 128;

    #pragma unroll 2
    for (int i = 0; i < 128; ++i) {
        const int k = k0 + i;                  // wave-uniform -> s_load path
        const float* ck = cb + k * CDIM;
        const uint64_t* cq = (const uint64_t*)(const void*)ck; // {c[2m],c[2m+1]} pairs

        // einsum AVX512 order, packed chains pv[j] = {v[2j], v[2j+1]}:
        // v[l] = fma(z[l],c[l], fma(z[16+l],c[16+l], fma(z[32+l],c[32+l],
        //        fma(z[48+l],c[48+l], 0))))
        f2 pv[8];
        #pragma unroll
        for (int j = 0; j < 8; ++j) {
            pv[j] = pk_fma_s(zz2[j], cq[j],
                      pk_fma_s(zz2[8 + j], cq[8 + j],
                        pk_fma_s(zz2[16 + j], cq[16 + j],
                          pk_fma_s(zz2[24 + j], cq[24 + j], zero))));
        }
        // reduce_add tree (packed): pe[j]={e[2j],e[2j+1]}, pf[j]={f[2j],f[2j+1]}
        f2 pe0 = pk_add(pv[0], pv[4]), pe1 = pk_add(pv[1], pv[5]);
        f2 pe2 = pk_add(pv[2], pv[6]), pe3 = pk_add(pv[3], pv[7]);
        f2 pf0 = pk_add(pe0, pe2), pf1 = pk_add(pe1, pe3);
        f2 pt = pk_add(pf0, pf1);              // {f0+f2, f1+f3}
        float dot = pt.x + pt.y;               // (f0+f2) + (f1+f3)

        float A = sz + cnorm[k];               // fl(sz + sc_k)
        float d = fmaf(dot, -2.f, A);          // == fl(A - 2*dot): 2*dot exact

        if (d < best) { best = d; bk = k; }    // strict <: first occurrence
    }

    dcand[g * 64 + lane] = best;
    kcand[g * 64 + lane] = bk;
    __syncthreads();

    // combine over ascending k-ranges (strict < keeps first occurrence)
    float bd = dcand[lane];
    int bi = kcand[lane];
    #pragma unroll
    for (int gg = 1; gg < 4; ++gg) {
        float d2 = dcand[gg * 64 + lane];
        int   k2 = kcand[gg * 64 + lane];
        if (d2 < bd) { bd = d2; bi = k2; }
    }

    // indices (as float32, second output region) — wave 0 only
    if (g == 0) out[ZQ_ELEMS + n0 + lane] = (float)bi;

    // z_q: wave g writes channels [16g, 16g+16); coalesced 4B/lane stores
    const float* row = cb + (size_t)bi * CDIM;
    float* op = out + (size_t)b * CDIM * HW + hw0 + lane;
    #pragma unroll
    for (int c = 0; c < 16; ++c) {
        const int ch = g * 16 + c;
        op[(size_t)ch * HW] = row[ch];
    }
}

extern "C" void kernel_launch(void* const* d_in, const int* in_sizes, int n_in,
                              void* d_out, int out_size, void* d_ws, size_t ws_size,
                              hipStream_t stream) {
    const float* z_e = (const float*)d_in[0];
    const float* cb  = (const float*)d_in[1];
    float* out = (float*)d_out;

    float* cnorm_ws = nullptr;
    if (ws_size >= KCODES * sizeof(float)) {
        cnorm_ws = (float*)d_ws;
        cnorm_kernel<<<dim3(2), dim3(256), 0, stream>>>(cb, cnorm_ws);
    }
    vq_kernel<<<dim3(2048), dim3(256), 0, stream>>>(z_e, cb, cnorm_ws, out);
}

// Round 2
// 200.471 us; speedup vs baseline: 1.0491x; 1.0491x over previous
//
#include <hip/hip_runtime.h>
#include <stdint.h>

// VectorQuantizer — bit-exact replication of the fp32 numpy reference.
//   d = sum(z*z,1)[:,None] + sum(c*c,1)[None,:] - 2.0*einsum('nc,kc->nk',z,c)
// sums: numpy pairwise_sum n=64 (8 accumulators + fixed tree). einsum: AVX512
// order — 16 chained-FMA lanes over 4 blocks of 16, then reduce_add tree.
//
// Round 2 changes vs. round 1 (154µs steady):
//  (a) 2 POINTS PER LANE. v_pk_fma_f32 is half-rate per component on CDNA4
//      (fp32 peak 157.3 TF == scalar rate), so the VALU issue floor is
//      ~72µs, and the 154µs kernel was ~45% stalled on the per-iteration
//      codebook s_load (256B, sL1-miss, ~250cy; SGPR budget 102 forbids
//      double-buffering the row). Two points amortize one row-load over
//      ~2x the FMA work (~340cy/iter), so even 2-3 waves/SIMD saturate
//      the VALU. Also halves per-point loop/argmin/cnorm overhead.
//  (b) waves_per_eu(3) MIN ONLY (round-1's (4,4) max-cap made the
//      allocator park zz2 in AGPRs behind the asm's "v" constraints ->
//      v_accvgpr_read copies in the hot loop; VGPR_Count=56 < the 64
//      registers zz2 needs proved it). Budget 512/3=170 arch VGPRs fits
//      zza+zzb (128) + temps in VGPRs proper.
//  (c) dropped #pragma unroll 2 (neutral; SGPR pressure).
//
// Channel-pair packing proven bit-exact (prior session): VOP3P via inline
// asm, codebook row through SGPR pairs (wave-uniform s_load path, shared by
// both points), per-scalar ops and order identical to the scalar ref.
// Structure: 2 points/lane, 4-wave k-split (wave g: k in [128g,128g+128)),
// block = 128 points, 1024 blocks. Argmin over ascending disjoint k-ranges
// combined with strict < (first-occurrence preserved).

#pragma clang fp contract(off)

#define KCODES 512
#define CDIM 64
#define HW 4096              // 64*64
#define ZQ_ELEMS 8388608     // 32*64*64*64
#define NPB 128              // points per block

typedef float f2 __attribute__((ext_vector_type(2)));

// d = {fma(a.x, b.lo, c.x), fma(a.y, b.hi, c.y)} — b is an SGPR pair
static __device__ __forceinline__ f2 pk_fma_s(f2 a, uint64_t b, f2 c) {
    f2 d;
    asm("v_pk_fma_f32 %0, %1, %2, %3" : "=v"(d) : "v"(a), "s"(b), "v"(c));
    return d;
}
static __device__ __forceinline__ f2 pk_add(f2 a, f2 b) {
    f2 d;
    asm("v_pk_add_f32 %0, %1, %2" : "=v"(d) : "v"(a), "v"(b));
    return d;
}

// np.sum(row*row): pairwise_sum n=64 replica (products pre-rounded), one row
static __device__ __forceinline__ float cnorm_row(const float* __restrict__ row) {
    float r[8];
    #pragma unroll
    for (int j = 0; j < 8; ++j) r[j] = row[j] * row[j];
    #pragma unroll
    for (int i = 8; i < 64; i += 8) {
        #pragma unroll
        for (int j = 0; j < 8; ++j) r[j] = r[j] + row[i + j] * row[i + j];
    }
    return ((r[0] + r[1]) + (r[2] + r[3])) + ((r[4] + r[5]) + (r[6] + r[7]));
}

// np.sum(z*z, axis=1): pairwise replica, packed by channel pairs
static __device__ __forceinline__ float znorm_pairwise(const f2* zz2) {
    f2 pr[4];
    #pragma unroll
    for (int t = 0; t < 4; ++t) pr[t] = zz2[t] * zz2[t];
    #pragma unroll
    for (int i = 8; i < 64; i += 8) {
        #pragma unroll
        for (int t = 0; t < 4; ++t) {
            f2 zt = zz2[(i + 2 * t) / 2];
            pr[t] = pr[t] + zt * zt;
        }
    }
    float s01 = pr[0].x + pr[0].y;
    float s23 = pr[1].x + pr[1].y;
    float s45 = pr[2].x + pr[2].y;
    float s67 = pr[3].x + pr[3].y;
    return (s01 + s23) + (s45 + s67);
}

// One-shot: cnorm[512] into workspace. 2 blocks x 256 threads.
__global__ void cnorm_kernel(const float* __restrict__ cb,
                             float* __restrict__ cnorm_out) {
    int k = (int)blockIdx.x * 256 + (int)threadIdx.x;
    if (k < KCODES) cnorm_out[k] = cnorm_row(cb + (size_t)k * CDIM);
}

__global__ __launch_bounds__(256)
__attribute__((amdgpu_waves_per_eu(3)))
void vq_kernel(
    const float* __restrict__ z_e,
    const float* __restrict__ cb,
    const float* __restrict__ cnorm_g,   // precomputed (d_ws) or nullptr
    float* __restrict__ out)
{
    __shared__ float cnorm[KCODES];
    __shared__ float dcand[4 * NPB];
    __shared__ int   kcand[4 * NPB];
    __shared__ int   kbest[NPB];

    if (cnorm_g) {
        #pragma unroll
        for (int k = (int)threadIdx.x; k < KCODES; k += 256)
            cnorm[k] = cnorm_g[k];
    } else {
        for (int k = (int)threadIdx.x; k < KCODES; k += 256)
            cnorm[k] = cnorm_row(cb + (size_t)k * CDIM);
    }

    // block = 128 consecutive points; wave g covers k in [128g, 128g+128)
    const int lane = (int)threadIdx.x & 63;
    const int g = __builtin_amdgcn_readfirstlane((int)threadIdx.x >> 6);
    const int n0 = (int)blockIdx.x * NPB;
    const int b = n0 / HW;                 // NPB divides HW -> single image
    const int hw0 = n0 % HW;
    const float* zpa = z_e + (size_t)b * CDIM * HW + hw0 + lane;       // pt A
    const float* zpb = zpa + 64;                                       // pt B

    // two points per lane; channel pairs packed: zz[m] = {z[2m], z[2m+1]}
    f2 zza[CDIM / 2], zzb[CDIM / 2];
    #pragma unroll
    for (int m = 0; m < CDIM / 2; ++m) {
        f2 t;
        t.x = zpa[(size_t)(2 * m) * HW];
        t.y = zpa[(size_t)(2 * m + 1) * HW];
        zza[m] = t;
    }
    #pragma unroll
    for (int m = 0; m < CDIM / 2; ++m) {
        f2 t;
        t.x = zpb[(size_t)(2 * m) * HW];
        t.y = zpb[(size_t)(2 * m + 1) * HW];
        zzb[m] = t;
    }

    const float sza = znorm_pairwise(zza);
    const float szb = znorm_pairwise(zzb);

    __syncthreads();

    f2 zero; zero.x = 0.f; zero.y = 0.f;   // hoisted VGPR pair for chain tails

    float best_a = 3.4e38f, best_b = 3.4e38f;
    int bk_a = 0, bk_b = 0;
    const int k0 = g * 128;

    for (int i = 0; i < 128; ++i) {
        const int k = k0 + i;                  // wave-uniform -> s_load path
        const float* ck = cb + k * CDIM;
        const uint64_t* cq = (const uint64_t*)(const void*)ck; // {c[2m],c[2m+1]}
        const float A0 = cnorm[k];

        // ---- point A: einsum AVX512 order, packed chains ----
        // v[l] = fma(z[l],c[l], fma(z[16+l],c[16+l], fma(z[32+l],c[32+l],
        //        fma(z[48+l],c[48+l], 0))))
        {
            f2 pv[8];
            #pragma unroll
            for (int j = 0; j < 8; ++j) {
                pv[j] = pk_fma_s(zza[j], cq[j],
                          pk_fma_s(zza[8 + j], cq[8 + j],
                            pk_fma_s(zza[16 + j], cq[16 + j],
                              pk_fma_s(zza[24 + j], cq[24 + j], zero))));
            }
            f2 pe0 = pk_add(pv[0], pv[4]), pe1 = pk_add(pv[1], pv[5]);
            f2 pe2 = pk_add(pv[2], pv[6]), pe3 = pk_add(pv[3], pv[7]);
            f2 pf0 = pk_add(pe0, pe2), pf1 = pk_add(pe1, pe3);
            f2 pt = pk_add(pf0, pf1);
            float dot = pt.x + pt.y;
            float A = sza + A0;                // fl(sz + sc_k)
            float d = fmaf(dot, -2.f, A);      // == fl(A - 2*dot)
            if (d < best_a) { best_a = d; bk_a = k; }
        }

        // ---- point B: identical sequence, same SGPR row ----
        {
            f2 pv[8];
            #pragma unroll
            for (int j = 0; j < 8; ++j) {
                pv[j] = pk_fma_s(zzb[j], cq[j],
                          pk_fma_s(zzb[8 + j], cq[8 + j],
                            pk_fma_s(zzb[16 + j], cq[16 + j],
                              pk_fma_s(zzb[24 + j], cq[24 + j], zero))));
            }
            f2 pe0 = pk_add(pv[0], pv[4]), pe1 = pk_add(pv[1], pv[5]);
            f2 pe2 = pk_add(pv[2], pv[6]), pe3 = pk_add(pv[3], pv[7]);
            f2 pf0 = pk_add(pe0, pe2), pf1 = pk_add(pe1, pe3);
            f2 pt = pk_add(pf0, pf1);
            float dot = pt.x + pt.y;
            float A = szb + A0;
            float d = fmaf(dot, -2.f, A);
            if (d < best_b) { best_b = d; bk_b = k; }
        }
    }

    dcand[g * NPB + lane]      = best_a;
    kcand[g * NPB + lane]      = bk_a;
    dcand[g * NPB + 64 + lane] = best_b;
    kcand[g * NPB + 64 + lane] = bk_b;
    __syncthreads();

    // combine over ascending k-ranges (strict < keeps first occurrence)
    const int tid = (int)threadIdx.x;
    if (tid < NPB) {
        float bd = dcand[tid];
        int bi = kcand[tid];
        #pragma unroll
        for (int gg = 1; gg < 4; ++gg) {
            float d2 = dcand[gg * NPB + tid];
            int   k2 = kcand[gg * NPB + tid];
            if (d2 < bd) { bd = d2; bi = k2; }
        }
        out[ZQ_ELEMS + n0 + tid] = (float)bi;  // indices (as float32)
        kbest[tid] = bi;
    }
    __syncthreads();

    // z_q: wave g writes channels [16g, 16g+16) for both points; 4B/lane
    const int bi_a = kbest[lane];
    const int bi_b = kbest[64 + lane];
    const float* rowa = cb + (size_t)bi_a * CDIM;
    const float* rowb = cb + (size_t)bi_b * CDIM;
    float* opa = out + (size_t)b * CDIM * HW + hw0 + lane;
    float* opb = opa + 64;
    #pragma unroll
    for (int c = 0; c < 16; ++c) {
        const int ch = g * 16 + c;
        opa[(size_t)ch * HW] = rowa[ch];
        opb[(size_t)ch * HW] = rowb[ch];
    }
}

extern "C" void kernel_launch(void* const* d_in, const int* in_sizes, int n_in,
                              void* d_out, int out_size, void* d_ws, size_t ws_size,
                              hipStream_t stream) {
    const float* z_e = (const float*)d_in[0];
    const float* cb  = (const float*)d_in[1];
    float* out = (float*)d_out;

    float* cnorm_ws = nullptr;
    if (ws_size >= KCODES * sizeof(float)) {
        cnorm_ws = (float*)d_ws;
        cnorm_kernel<<<dim3(2), dim3(256), 0, stream>>>(cb, cnorm_ws);
    }
    vq_kernel<<<dim3(131072 / NPB), dim3(256), 0, stream>>>(z_e, cb, cnorm_ws, out);
}

// Round 3
// 193.555 us; speedup vs baseline: 1.0866x; 1.0357x over previous
//
#include <hip/hip_runtime.h>
#include <stdint.h>

// VectorQuantizer — bit-exact replication of the fp32 numpy reference.
//   d = sum(z*z,1)[:,None] + sum(c*c,1)[None,:] - 2.0*einsum('nc,kc->nk',z,c)
// sums: numpy pairwise_sum n=64 (8 accumulators + fixed tree). einsum: AVX512
// order — 16 chained-FMA lanes over 4 blocks of 16, then reduce_add tree.
//
// Round 3 theory: rounds 0-2 all pinned at ~155us because the allocator caps
// the ARCH vgpr file at 256/waves_target (r0: 48@4w, r1: 56@4w, r2: 84@3w —
// exactly 256/waves each time) and parks the overflow (zz arrays) in the
// AGPR half / scratch, adding copies on every hot-loop use. Every prior
// change just moved along that constraint line. Fix: 1 point/lane (live set
// ~105 regs) + amdgpu_waves_per_eu(2) min-only (arch quota 128 >= live set)
// -> nothing parked, pure pk_fma hot loop. HW occupancy follows ACTUAL usage
// (~110 regs -> 4 waves/SIMD), enough to hide the per-iter codebook s_load
// (~300cy) behind ~165cy/iter x 4 waves.
//
// Channel-pair packing proven bit-exact (prior session): VOP3P via inline
// asm, codebook row through SGPR pairs (wave-uniform s_load path), per-scalar
// ops and order identical to the scalar ref.
// Structure: 1 point/lane, 4-wave k-split (wave g: k in [128g,128g+128)),
// block = 64 points, 2048 blocks. Argmin over ascending disjoint k-ranges
// combined with strict < (first-occurrence preserved).

#pragma clang fp contract(off)

#define KCODES 512
#define CDIM 64
#define HW 4096              // 64*64
#define ZQ_ELEMS 8388608     // 32*64*64*64

typedef float f2 __attribute__((ext_vector_type(2)));

// d = {fma(a.x, b.lo, c.x), fma(a.y, b.hi, c.y)} — b is an SGPR pair
static __device__ __forceinline__ f2 pk_fma_s(f2 a, uint64_t b, f2 c) {
    f2 d;
    asm("v_pk_fma_f32 %0, %1, %2, %3" : "=v"(d) : "v"(a), "s"(b), "v"(c));
    return d;
}
static __device__ __forceinline__ f2 pk_add(f2 a, f2 b) {
    f2 d;
    asm("v_pk_add_f32 %0, %1, %2" : "=v"(d) : "v"(a), "v"(b));
    return d;
}

// np.sum(row*row): pairwise_sum n=64 replica (products pre-rounded), one row
static __device__ __forceinline__ float cnorm_row(const float* __restrict__ row) {
    float r[8];
    #pragma unroll
    for (int j = 0; j < 8; ++j) r[j] = row[j] * row[j];
    #pragma unroll
    for (int i = 8; i < 64; i += 8) {
        #pragma unroll
        for (int j = 0; j < 8; ++j) r[j] = r[j] + row[i + j] * row[i + j];
    }
    return ((r[0] + r[1]) + (r[2] + r[3])) + ((r[4] + r[5]) + (r[6] + r[7]));
}

// One-shot: cnorm[512] into workspace. 2 blocks x 256 threads.
__global__ void cnorm_kernel(const float* __restrict__ cb,
                             float* __restrict__ cnorm_out) {
    int k = (int)blockIdx.x * 256 + (int)threadIdx.x;
    if (k < KCODES) cnorm_out[k] = cnorm_row(cb + (size_t)k * CDIM);
}

__global__ __launch_bounds__(256)
__attribute__((amdgpu_waves_per_eu(2)))   // min-only: arch quota 128 >= live ~105
void vq_kernel(
    const float* __restrict__ z_e,
    const float* __restrict__ cb,
    const float* __restrict__ cnorm_g,   // precomputed (d_ws) or nullptr
    float* __restrict__ out)
{
    __shared__ float cnorm[KCODES];
    __shared__ float dcand[4 * 64];
    __shared__ int   kcand[4 * 64];

    if (cnorm_g) {
        // coalesced 2KB load: 2 x 4B/lane, stride-1
        #pragma unroll
        for (int k = (int)threadIdx.x; k < KCODES; k += 256)
            cnorm[k] = cnorm_g[k];
    } else {
        // fallback (ws too small): original in-block compute, bit-identical
        for (int k = (int)threadIdx.x; k < KCODES; k += 256)
            cnorm[k] = cnorm_row(cb + (size_t)k * CDIM);
    }

    // block = 64 consecutive points; wave g covers k in [128g, 128g+128)
    const int lane = (int)threadIdx.x & 63;
    const int g = __builtin_amdgcn_readfirstlane((int)threadIdx.x >> 6);
    const int n0 = (int)blockIdx.x * 64;
    const int b = n0 / HW;
    const int hw0 = n0 % HW;
    const float* zp = z_e + (size_t)b * CDIM * HW + hw0 + lane;

    // one point per lane; channel pairs packed: zz2[m] = {z[2m], z[2m+1]}
    f2 zz2[CDIM / 2];
    #pragma unroll
    for (int m = 0; m < CDIM / 2; ++m) {
        f2 t;
        t.x = zp[(size_t)(2 * m) * HW];
        t.y = zp[(size_t)(2 * m + 1) * HW];
        zz2[m] = t;
    }

    // np.sum(z*z, axis=1): pairwise replica, packed by channel pairs
    float sz;
    {
        f2 pr[4];
        #pragma unroll
        for (int t = 0; t < 4; ++t) pr[t] = zz2[t] * zz2[t];
        #pragma unroll
        for (int i = 8; i < 64; i += 8) {
            #pragma unroll
            for (int t = 0; t < 4; ++t) {
                f2 zt = zz2[(i + 2 * t) / 2];
                pr[t] = pr[t] + zt * zt;
            }
        }
        float s01 = pr[0].x + pr[0].y;
        float s23 = pr[1].x + pr[1].y;
        float s45 = pr[2].x + pr[2].y;
        float s67 = pr[3].x + pr[3].y;
        sz = (s01 + s23) + (s45 + s67);
    }

    __syncthreads();

    f2 zero; zero.x = 0.f; zero.y = 0.f;   // hoisted VGPR pair for chain tails

    float best = 3.4e38f;
    int bk = 0;
    const int k0 = g * 128;

    for (int i = 0; i < 128; ++i) {
        const int k = k0 + i;                  // wave-uniform -> s_load path
        const float* ck = cb + k * CDIM;
        const uint64_t* cq = (const uint64_t*)(const void*)ck; // {c[2m],c[2m+1]} pairs

        // einsum AVX512 order, packed chains pv[j] = {v[2j], v[2j+1]}:
        // v[l] = fma(z[l],c[l], fma(z[16+l],c[16+l], fma(z[32+l],c[32+l],
        //        fma(z[48+l],c[48+l], 0))))
        f2 pv[8];
        #pragma unroll
        for (int j = 0; j < 8; ++j) {
            pv[j] = pk_fma_s(zz2[j], cq[j],
                      pk_fma_s(zz2[8 + j], cq[8 + j],
                        pk_fma_s(zz2[16 + j], cq[16 + j],
                          pk_fma_s(zz2[24 + j], cq[24 + j], zero))));
        }
        // reduce_add tree (packed): pe[j]={e[2j],e[2j+1]}, pf[j]={f[2j],f[2j+1]}
        f2 pe0 = pk_add(pv[0], pv[4]), pe1 = pk_add(pv[1], pv[5]);
        f2 pe2 = pk_add(pv[2], pv[6]), pe3 = pk_add(pv[3], pv[7]);
        f2 pf0 = pk_add(pe0, pe2), pf1 = pk_add(pe1, pe3);
        f2 pt = pk_add(pf0, pf1);              // {f0+f2, f1+f3}
        float dot = pt.x + pt.y;               // (f0+f2) + (f1+f3)

        float A = sz + cnorm[k];               // fl(sz + sc_k)
        float d = fmaf(dot, -2.f, A);          // == fl(A - 2*dot): 2*dot exact

        if (d < best) { best = d; bk = k; }    // strict <: first occurrence
    }

    dcand[g * 64 + lane] = best;
    kcand[g * 64 + lane] = bk;
    __syncthreads();

    // combine over ascending k-ranges (strict < keeps first occurrence)
    float bd = dcand[lane];
    int bi = kcand[lane];
    #pragma unroll
    for (int gg = 1; gg < 4; ++gg) {
        float d2 = dcand[gg * 64 + lane];
        int   k2 = kcand[gg * 64 + lane];
        if (d2 < bd) { bd = d2; bi = k2; }
    }

    // indices (as float32, second output region) — wave 0 only
    if (g == 0) out[ZQ_ELEMS + n0 + lane] = (float)bi;

    // z_q: wave g writes channels [16g, 16g+16); coalesced 4B/lane stores
    const float* row = cb + (size_t)bi * CDIM;
    float* op = out + (size_t)b * CDIM * HW + hw0 + lane;
    #pragma unroll
    for (int c = 0; c < 16; ++c) {
        const int ch = g * 16 + c;
        op[(size_t)ch * HW] = row[ch];
    }
}

extern "C" void kernel_launch(void* const* d_in, const int* in_sizes, int n_in,
                              void* d_out, int out_size, void* d_ws, size_t ws_size,
                              hipStream_t stream) {
    const float* z_e = (const float*)d_in[0];
    const float* cb  = (const float*)d_in[1];
    float* out = (float*)d_out;

    float* cnorm_ws = nullptr;
    if (ws_size >= KCODES * sizeof(float)) {
        cnorm_ws = (float*)d_ws;
        cnorm_kernel<<<dim3(2), dim3(256), 0, stream>>>(cb, cnorm_ws);
    }
    vq_kernel<<<dim3(2048), dim3(256), 0, stream>>>(z_e, cb, cnorm_ws, out);
}